// Round 2
// baseline (747.232 us; speedup 1.0000x reference)
//
#include <hip/hip_runtime.h>
#include <stdint.h>

// Problem dims
#define NB  256
#define NT  100
#define NIN 128
#define NH  1024
#define NOUT 35
#define NR  25600           // NT*NB rows

// d_out float offsets
#define O_SPK2 26214400ull
#define O_SPK3 52428800ull
#define O_SPK4 78643200ull
#define O_MEM4 79539200ull

// d_ws byte offsets
#define WS_KBUF 0ull           // 25600*1024*2 = 52428800 (K2, then K3, then K4[25600*128*2])
#define WS_SPKB 52428800ull    // 25600*1024 i8 = 26214400 (spk bytes, reused per layer)
#define WS_K2B  78643200ull    // 1024*1024 i8
#define WS_K3B  79691776ull    // 1024*1024 i8
#define WS_K4B  80740352ull    // 128*1024 i8 (rows 35..127 zero)
#define WS_Q1T  80871424ull    // 128*1024 f32 = 524288
#define WS_N1   81395712ull    // 25600 u32
#define WS_N2   81498112ull
#define WS_N3   81600512ull
// end 81702912 (~78 MB)

#define S2C ((float)((1.0 - 0.001) / 15.0))
#define S1C ((float)(1.0 / 15.0))

typedef int v4i __attribute__((ext_vector_type(4)));

__device__ __forceinline__ void async16(const void* g, void* l) {
  __builtin_amdgcn_global_load_lds((const __attribute__((address_space(1))) uint32_t*)g,
                                   (__attribute__((address_space(3))) uint32_t*)l, 16, 0, 0);
}

__device__ __forceinline__ uint8_t qk(float w) {   // k-index 0..15 for (0.001,1.0) quant
  float wc = fminf(fmaxf(w, 0.001f), 1.0f);
  return (uint8_t)(int)rintf((wc - 0.001f) / S2C);
}

// ------------------------------------------------------------------
// K1: elementwise weight quantization (all coalesced) + q1T + zero n
// ------------------------------------------------------------------
__global__ void k_prep(const float* __restrict__ w1, const float* __restrict__ w2,
                       const float* __restrict__ w3, const float* __restrict__ w4,
                       uint8_t* __restrict__ ws)
{
  long long id = (long long)blockIdx.x * 256 + threadIdx.x;
  if (id < 1048576) { ws[WS_K2B + id] = qk(w2[id]); return; }
  id -= 1048576;
  if (id < 1048576) { ws[WS_K3B + id] = qk(w3[id]); return; }
  id -= 1048576;
  if (id < 131072) {                       // k4b[j][i], j<35 real else 0
    int j = (int)(id >> 10), i = (int)(id & 1023);
    ws[WS_K4B + id] = (j < NOUT) ? qk(w4[(size_t)j * 1024 + i]) : (uint8_t)0;
    return;
  }
  id -= 131072;
  if (id < 131072) {                       // q1T[i*1024+j] = fake_quant(w1[j][i]) fp32
    int i = (int)(id >> 10), j = (int)(id & 1023);
    float wv = w1[(size_t)j * 128 + i];
    float wc = fminf(fmaxf(wv, -0.5f), 0.5f);
    float q = rintf((wc + 0.5f) / S1C) * S1C - 0.5f;
    ((float*)(ws + WS_Q1T))[id] = q;
    return;
  }
  id -= 131072;
  if (id < 76800) ((uint32_t*)(ws + WS_N1))[id] = 0;   // zero n1,n2,n3 (contiguous)
}

// ------------------------------------------------------------------
// K2: cur1[(t*256+b)][j] = dot(x[b,t,:]/15, q1T[:,j]) fp32, into spk1 region
// ------------------------------------------------------------------
__global__ __launch_bounds__(256) void k_cur1(const float* __restrict__ x,
                                              const uint8_t* __restrict__ ws,
                                              float* __restrict__ out)
{
  __shared__ float xsT[128 * 68];   // [i][r], padded stride 68
  __shared__ float qch[16 * 256];   // [ii][j] chunk of q1T
  const float* q1T = (const float*)(ws + WS_Q1T);
  const int tid = threadIdx.x;
  const int rb = blockIdx.x >> 2, cb = blockIdx.x & 3;
  const int t = rb >> 2, b0 = (rb & 3) * 64;     // rows rb*64.. = (t*256 + b0 + r)
  const int jI = tid & 63, rI = tid >> 6;
  const int j4 = jI * 4, r16 = rI * 16;

  #pragma unroll
  for (int k = 0; k < 32; ++k) {
    int e = tid + k * 256;
    int r = e >> 7, i = e & 127;
    xsT[i * 68 + r] = x[((size_t)(b0 + r) * NT + t) * NIN + i] / 15.0f;
  }
  float acc[16][4];
  #pragma unroll
  for (int d = 0; d < 16; ++d) { acc[d][0]=0.f; acc[d][1]=0.f; acc[d][2]=0.f; acc[d][3]=0.f; }
  for (int ic = 0; ic < 8; ++ic) {
    __syncthreads();
    #pragma unroll
    for (int k = 0; k < 16; ++k) {
      int e = tid + k * 256;
      int ii = e >> 8, j = e & 255;
      qch[ii * 256 + j] = q1T[((size_t)(ic * 16 + ii) << 10) + cb * 256 + j];
    }
    __syncthreads();
    #pragma unroll
    for (int ii = 0; ii < 16; ++ii) {
      int i = ic * 16 + ii;
      const float4 q  = *(const float4*)&qch[ii * 256 + j4];
      const float4 xa = *(const float4*)&xsT[i * 68 + r16];
      const float4 xb = *(const float4*)&xsT[i * 68 + r16 + 4];
      const float4 xc = *(const float4*)&xsT[i * 68 + r16 + 8];
      const float4 xd = *(const float4*)&xsT[i * 68 + r16 + 12];
      float xr[16];
      xr[0]=xa.x; xr[1]=xa.y; xr[2]=xa.z; xr[3]=xa.w;
      xr[4]=xb.x; xr[5]=xb.y; xr[6]=xb.z; xr[7]=xb.w;
      xr[8]=xc.x; xr[9]=xc.y; xr[10]=xc.z; xr[11]=xc.w;
      xr[12]=xd.x; xr[13]=xd.y; xr[14]=xd.z; xr[15]=xd.w;
      #pragma unroll
      for (int d = 0; d < 16; ++d) {
        acc[d][0] = fmaf(xr[d], q.x, acc[d][0]);
        acc[d][1] = fmaf(xr[d], q.y, acc[d][1]);
        acc[d][2] = fmaf(xr[d], q.z, acc[d][2]);
        acc[d][3] = fmaf(xr[d], q.w, acc[d][3]);
      }
    }
  }
  #pragma unroll
  for (int d = 0; d < 16; ++d) {
    float4 v = make_float4(acc[d][0], acc[d][1], acc[d][2], acc[d][3]);
    *(float4*)&out[((size_t)rb * 64 + r16 + d) * 1024 + cb * 256 + j4] = v;
  }
}

// ------------------------------------------------------------------
// K3: layer-1 membrane scan: cur1 (in out) -> spk1 floats (in place)
//     + spk bytes + n1 counts
// ------------------------------------------------------------------
__global__ __launch_bounds__(256) void k_scan1(uint8_t* __restrict__ ws, float* __restrict__ out)
{
  const int tid = threadIdx.x;
  const int b = blockIdx.x >> 2;
  const int j = (blockIdx.x & 3) * 256 + tid;
  uint8_t* spkb = ws + WS_SPKB;
  uint32_t* n1 = (uint32_t*)(ws + WS_N1);
  const size_t stride = (size_t)NB * NH;
  size_t idx = (size_t)b * NH + j;
  float m = 0.f;
  float c = out[idx];
  for (int t = 0; t < NT; ++t) {
    float cn = (t + 1 < NT) ? out[idx + stride] : 0.f;
    float rst = m > 1.0f ? 1.0f : 0.0f;
    m = fmaf(0.9f, m, c) - rst;
    bool sp = (m - 1.0f) > 0.0f;
    out[idx] = sp ? 1.0f : 0.0f;
    spkb[idx] = sp ? 1 : 0;
    unsigned long long bal = __ballot(sp);
    if ((tid & 63) == 0) atomicAdd((unsigned int*)&n1[t * NB + b], (unsigned)__popcll(bal));
    idx += stride; c = cn;
  }
}

// ------------------------------------------------------------------
// K4: i8 MFMA GEMM: C[r][j] = sum_k A[r][k]*B[j][k], A spk bytes [NR x 1024],
//     B k-bytes [N x 1024] row-major, C u16 [NR x (ncb*128)].
//     Block tile 128x128, K-stage 128, 4 waves (2x2 of 64x64).
// ------------------------------------------------------------------
__global__ __launch_bounds__(256) void k_gemm(const uint8_t* __restrict__ A,
                                              const uint8_t* __restrict__ Bm,
                                              uint16_t* __restrict__ C, int ncb)
{
  __shared__ uint8_t sA[16384];   // [kh(2)][cm(8)][lane*16]  (kh*8+cm)*1024
  __shared__ uint8_t sB[16384];
  const int tid = threadIdx.x, lane = tid & 63, wave = tid >> 6;
  const int lm = lane & 15, lk = lane >> 4;
  const int rb = blockIdx.x, jb = blockIdx.y;
  const int mw = wave & 1, nw = wave >> 1;
  v4i acc[4][4];
  #pragma unroll
  for (int a = 0; a < 4; ++a)
    #pragma unroll
    for (int bb = 0; bb < 4; ++bb) { acc[a][bb][0]=0; acc[a][bb][1]=0; acc[a][bb][2]=0; acc[a][bb][3]=0; }

  for (int kk = 0; kk < 1024; kk += 128) {
    __syncthreads();
    #pragma unroll
    for (int q = 0; q < 8; ++q) {
      int cid = wave * 8 + q;          // 0..31
      if (cid < 16) {                  // A chunk: kh = cid>>3, cm = cid&7
        int kh = cid >> 3, cm = cid & 7;
        const uint8_t* g = A + (size_t)(rb * 128 + cm * 16 + lm) * 1024 + kk + kh * 64 + (lk << 4);
        async16(g, sA + cid * 1024);
      } else {
        int cb2 = cid - 16;
        int kh = cb2 >> 3, cn = cb2 & 7;
        const uint8_t* g = Bm + (size_t)(jb * 128 + cn * 16 + lm) * 1024 + kk + kh * 64 + (lk << 4);
        async16(g, sB + cb2 * 1024);
      }
    }
    __syncthreads();
    #pragma unroll
    for (int kh = 0; kh < 2; ++kh) {
      v4i av[4], bv[4];
      #pragma unroll
      for (int mi = 0; mi < 4; ++mi)
        av[mi] = *(const v4i*)(sA + (size_t)(kh * 8 + mw * 4 + mi) * 1024 + lane * 16);
      #pragma unroll
      for (int ni = 0; ni < 4; ++ni)
        bv[ni] = *(const v4i*)(sB + (size_t)(kh * 8 + nw * 4 + ni) * 1024 + lane * 16);
      #pragma unroll
      for (int mi = 0; mi < 4; ++mi)
        #pragma unroll
        for (int ni = 0; ni < 4; ++ni)
          acc[mi][ni] = __builtin_amdgcn_mfma_i32_16x16x64_i8(av[mi], bv[ni], acc[mi][ni], 0, 0, 0);
    }
  }
  const int rowb = rb * 128 + mw * 64;
  const int colb = jb * 128 + nw * 64;
  const int strideC = ncb * 128;
  #pragma unroll
  for (int mi = 0; mi < 4; ++mi)
    #pragma unroll
    for (int ni = 0; ni < 4; ++ni)
      #pragma unroll
      for (int r = 0; r < 4; ++r) {
        int row = rowb + mi * 16 + (lane >> 4) * 4 + r;
        int col = colb + ni * 16 + (lane & 15);
        C[(size_t)row * strideC + col] = (uint16_t)acc[mi][ni][r];
      }
}

// ------------------------------------------------------------------
// K5: hidden-layer membrane scan (layers 2,3): K u16 + n_prev -> spk floats
//     + spk bytes + n_out
// ------------------------------------------------------------------
__global__ __launch_bounds__(256) void k_scan23(const uint16_t* __restrict__ Kin,
                                                const uint32_t* __restrict__ nprev,
                                                uint32_t* __restrict__ nout,
                                                float beta,
                                                float* __restrict__ outB,
                                                uint8_t* __restrict__ spkb)
{
  const int tid = threadIdx.x;
  const int b = blockIdx.x >> 2;
  const int j = (blockIdx.x & 3) * 256 + tid;
  const size_t stride = (size_t)NB * NH;
  size_t idx = (size_t)b * NH + j;
  float m = 0.f;
  uint16_t kv = Kin[idx];
  for (int t = 0; t < NT; ++t) {
    uint16_t kn = (t + 1 < NT) ? Kin[idx + stride] : (uint16_t)0;
    float nb = 0.001f * (float)nprev[t * NB + b];
    float cur = fmaf(S2C, (float)kv, nb);
    float rst = m > 1.0f ? 1.0f : 0.0f;
    m = fmaf(beta, m, cur) - rst;
    bool sp = (m - 1.0f) > 0.0f;
    outB[idx] = sp ? 1.0f : 0.0f;
    spkb[idx] = sp ? 1 : 0;
    unsigned long long bal = __ballot(sp);
    if ((tid & 63) == 0) atomicAdd((unsigned int*)&nout[t * NB + b], (unsigned)__popcll(bal));
    idx += stride; kv = kn;
  }
}

// ------------------------------------------------------------------
// K6: layer-4 scan (zero-reset): K4 u16 [NR x 128] + n3 -> spk4, mem4
// ------------------------------------------------------------------
__global__ __launch_bounds__(64) void k_scan4(const uint8_t* __restrict__ ws, float* __restrict__ out)
{
  const int b = blockIdx.x;
  const int j = threadIdx.x;
  const uint16_t* K4 = (const uint16_t*)(ws + WS_KBUF);
  const uint32_t* n3 = (const uint32_t*)(ws + WS_N3);
  size_t idx = (size_t)b * 128 + j;
  const size_t stride = (size_t)NB * 128;
  float m = 0.f;
  uint16_t kv = (j < NOUT) ? K4[idx] : (uint16_t)0;
  for (int t = 0; t < NT; ++t) {
    uint16_t kn = (t + 1 < NT && j < NOUT) ? K4[idx + stride] : (uint16_t)0;
    float cur = fmaf(S2C, (float)kv, 0.001f * (float)n3[t * NB + b]);
    float rst = m > 1.0f ? 1.0f : 0.0f;
    float bsv = fmaf(0.95f, m, cur);
    m = (rst > 0.0f) ? 0.0f : bsv;
    if (j < NOUT) {
      size_t rowO = ((size_t)t * NB + b) * NOUT + j;
      out[O_SPK4 + rowO] = ((m - 1.0f) > 0.0f) ? 1.0f : 0.0f;
      out[O_MEM4 + rowO] = m;
    }
    idx += stride; kv = kn;
  }
}

extern "C" void kernel_launch(void* const* d_in, const int* in_sizes, int n_in,
                              void* d_out, int out_size, void* d_ws, size_t ws_size,
                              hipStream_t stream)
{
  const float* x  = (const float*)d_in[0];
  const float* w1 = (const float*)d_in[1];
  const float* w2 = (const float*)d_in[2];
  const float* w3 = (const float*)d_in[3];
  const float* w4 = (const float*)d_in[4];
  float* out = (float*)d_out;
  uint8_t* ws = (uint8_t*)d_ws;

  uint16_t* KBUF = (uint16_t*)(ws + WS_KBUF);
  uint8_t*  SPKB = ws + WS_SPKB;
  uint32_t* N1 = (uint32_t*)(ws + WS_N1);
  uint32_t* N2 = (uint32_t*)(ws + WS_N2);
  uint32_t* N3 = (uint32_t*)(ws + WS_N3);

  hipLaunchKernelGGL(k_prep, dim3(9517), dim3(256), 0, stream, w1, w2, w3, w4, ws);
  hipLaunchKernelGGL(k_cur1, dim3(1600), dim3(256), 0, stream, x, ws, out);
  hipLaunchKernelGGL(k_scan1, dim3(1024), dim3(256), 0, stream, ws, out);
  hipLaunchKernelGGL(k_gemm, dim3(200, 8), dim3(256), 0, stream, SPKB, ws + WS_K2B, KBUF, 8);
  hipLaunchKernelGGL(k_scan23, dim3(1024), dim3(256), 0, stream, KBUF, N1, N2, 0.85f, out + O_SPK2, SPKB);
  hipLaunchKernelGGL(k_gemm, dim3(200, 8), dim3(256), 0, stream, SPKB, ws + WS_K3B, KBUF, 8);
  hipLaunchKernelGGL(k_scan23, dim3(1024), dim3(256), 0, stream, KBUF, N2, N3, 0.8f, out + O_SPK3, SPKB);
  hipLaunchKernelGGL(k_gemm, dim3(200, 1), dim3(256), 0, stream, SPKB, ws + WS_K4B, KBUF, 1);
  hipLaunchKernelGGL(k_scan4, dim3(256), dim3(64), 0, stream, ws, out);
}